// Round 2
// baseline (139637.830 us; speedup 1.0000x reference)
//
#include <hip/hip_runtime.h>

#define F     4096
#define T     2048
#define ODIM  512
#define NBLK  256
#define NTHR  1024

// d_ws layout:
//   [0, 1024)      : arrive[256]  (u32 per block, monotone step counter)
//   [1280, 1284)   : release      (u32, monotone)
//   [4096, 36864)  : gfeats[2][4096] float ping-pong buffers
// kernel_launch memsets [0,4096) to zero on the stream before the kernel.

template <int CTRL>
__device__ __forceinline__ float dpp_add(float x) {
    int xi = __builtin_bit_cast(int, x);
    int yi = __builtin_amdgcn_update_dpp(0, xi, CTRL, 0xf, 0xf, false);
    return x + __builtin_bit_cast(float, yi);
}

// Full wave64 sum; total lands in lane 63. VALU-only (no LDS-pipe shuffles).
__device__ __forceinline__ float wave_sum(float x) {
    x = dpp_add<0x111>(x); // row_shr:1
    x = dpp_add<0x112>(x); // row_shr:2
    x = dpp_add<0x114>(x); // row_shr:4
    x = dpp_add<0x118>(x); // row_shr:8  -> lane15 of each row has row sum
    x = dpp_add<0x142>(x); // row_bcast:15
    x = dpp_add<0x143>(x); // row_bcast:31 -> lane63 has full sum
    return x;
}

__global__ __launch_bounds__(NTHR, 4) void rc_kernel(
    const float* __restrict__ x, const float* __restrict__ Wres,
    const float* __restrict__ wout, float* __restrict__ out,
    unsigned int* __restrict__ bar, float* __restrict__ gfeats)
{
    __shared__ __align__(16) float feats[F];   // 16 KB: current feats vector
    __shared__ float red[16][4];               // per-wave matvec partials
    __shared__ float redo[16];                 // per-wave out partials

    const int tid  = threadIdx.x;
    const int b    = blockIdx.x;
    const int w    = tid >> 6;
    const int lane = tid & 63;
    const int wr   = w & 3;   // row-group (4 rows each)
    const int wk   = w >> 2;  // k-group (1024 k each)

    // ---- persistent W_res fragment: 4 rows x 16 k = 64 fp32 regs ----
    // lane covers k = wk*1024 + i*256 + lane*4 + c   (i=0..3, c=0..3)
    const int row0 = b * 16 + wr * 4;
    float4 wreg[4][4];
    {
        const int kbase = wk * 1024 + lane * 4;
#pragma unroll
        for (int j = 0; j < 4; ++j) {
            const float* wp = Wres + (size_t)(row0 + j) * F + kbase;
#pragma unroll
            for (int i = 0; i < 4; ++i)
                wreg[j][i] = *(const float4*)(wp + i * 256);
        }
    }

    // ---- persistent w_out fragment: 8 fp32 regs ----
    // thread handles out row o = b*2 + tid/512, k = kk..kk+3 and 2048+kk..+3
    const int o  = tid >> 9;
    const int kk = (tid & 511) * 4;
    const float4 wo_a = *(const float4*)(wout + (size_t)(b * 2 + o) * F + kk);
    const float4 wo_b = *(const float4*)(wout + (size_t)(b * 2 + o) * F + 2048 + kk);

    // ---- init ----
    for (int i = tid; i < F; i += NTHR) feats[i] = 0.f;  // feats_{-1} = 0
    float xval = 0.f;
    if (tid < 16) xval = x[(size_t)(b * 16 + tid) * T + 0];
    __syncthreads();

    unsigned int* arrive  = bar;        // [0..255]
    unsigned int* release = bar + 320;  // own cacheline

    const float4* f4base = (const float4*)feats + wk * 256 + lane;

    for (int t = 0; t < T; ++t) {
        // ---- 1. matvec partials: 64 FMAs/lane on register weights ----
        float acc0 = 0.f, acc1 = 0.f, acc2 = 0.f, acc3 = 0.f;
#pragma unroll
        for (int i = 0; i < 4; ++i) {
            float4 f = f4base[i * 64];  // stride-1 across lanes: conflict-free b128
            acc0 += wreg[0][i].x * f.x + wreg[0][i].y * f.y + wreg[0][i].z * f.z + wreg[0][i].w * f.w;
            acc1 += wreg[1][i].x * f.x + wreg[1][i].y * f.y + wreg[1][i].z * f.z + wreg[1][i].w * f.w;
            acc2 += wreg[2][i].x * f.x + wreg[2][i].y * f.y + wreg[2][i].z * f.z + wreg[2][i].w * f.w;
            acc3 += wreg[3][i].x * f.x + wreg[3][i].y * f.y + wreg[3][i].z * f.z + wreg[3][i].w * f.w;
        }
        // ---- 2. wave-level reduce (VALU DPP), lane63 -> LDS ----
        acc0 = wave_sum(acc0);
        acc1 = wave_sum(acc1);
        acc2 = wave_sum(acc2);
        acc3 = wave_sum(acc3);
        if (lane == 63) {
            red[w][0] = acc0; red[w][1] = acc1; red[w][2] = acc2; red[w][3] = acc3;
        }
        __syncthreads();  // (A)

        // ---- 3. cross-wave reduce, clamp, publish 16 feats components ----
        float* gcur = gfeats + (size_t)(t & 1) * F;
        if (tid < 16) {
            const int r = tid;
            const int rw = r >> 2, rj = r & 3;
            float s = red[rw][rj] + red[rw + 4][rj] + red[rw + 8][rj] + red[rw + 12][rj];
            s += xval;
            s = fminf(1.f, fmaxf(-1.f, s));
            gcur[b * 16 + r] = s;
            const int tn = (t + 1 < T) ? (t + 1) : t;
            xval = x[(size_t)(b * 16 + r) * T + tn];  // prefetch next x
            __threadfence();  // release: drain stores before signaling
        }
        __syncthreads();  // (B)

        // ---- 4. grid barrier (wave 0 only; others park at (C)) ----
        if (w == 0) {
            const unsigned int tgt = (unsigned int)(t + 1);
            if (lane == 0)
                __hip_atomic_store(&arrive[b], tgt, __ATOMIC_RELEASE, __HIP_MEMORY_SCOPE_AGENT);
            if (b == 0) {
                bool ok;
                do {
                    unsigned a0 = __hip_atomic_load(&arrive[4 * lane + 0], __ATOMIC_RELAXED, __HIP_MEMORY_SCOPE_AGENT);
                    unsigned a1 = __hip_atomic_load(&arrive[4 * lane + 1], __ATOMIC_RELAXED, __HIP_MEMORY_SCOPE_AGENT);
                    unsigned a2 = __hip_atomic_load(&arrive[4 * lane + 2], __ATOMIC_RELAXED, __HIP_MEMORY_SCOPE_AGENT);
                    unsigned a3 = __hip_atomic_load(&arrive[4 * lane + 3], __ATOMIC_RELAXED, __HIP_MEMORY_SCOPE_AGENT);
                    ok = (a0 >= tgt) && (a1 >= tgt) && (a2 >= tgt) && (a3 >= tgt);
                } while (!__all(ok));
                if (lane == 0)
                    __hip_atomic_store(release, tgt, __ATOMIC_RELEASE, __HIP_MEMORY_SCOPE_AGENT);
            } else if (lane == 0) {
                while (__hip_atomic_load(release, __ATOMIC_RELAXED, __HIP_MEMORY_SCOPE_AGENT) < tgt) { }
            }
        }
        __syncthreads();  // (C)
        __threadfence();  // acquire: invalidate L1 before reading peers' feats

        // ---- 5. stage full feats_t: global -> LDS (1 float4/thread) ----
        float4 v = ((const float4*)gcur)[tid];
        ((float4*)feats)[tid] = v;
        __syncthreads();  // (D)

        // ---- 6. readout: out[o, t] = w_out[o] . feats_t ----
        const float4* fo = (const float4*)feats;
        float4 fa = fo[tid & 511];
        float4 fb = fo[512 + (tid & 511)];
        float p = wo_a.x * fa.x + wo_a.y * fa.y + wo_a.z * fa.z + wo_a.w * fa.w
                + wo_b.x * fb.x + wo_b.y * fb.y + wo_b.z * fb.z + wo_b.w * fb.w;
        p = wave_sum(p);
        if (lane == 63) redo[w] = p;
        __syncthreads();  // (E)
        if (tid < 2) {
            float s = 0.f;
#pragma unroll
            for (int i = 0; i < 8; ++i) s += redo[tid * 8 + i];
            out[(size_t)(b * 2 + tid) * T + t] = s;
        }
    }
}

extern "C" void kernel_launch(void* const* d_in, const int* in_sizes, int n_in,
                              void* d_out, int out_size, void* d_ws, size_t ws_size,
                              hipStream_t stream) {
    const float* x    = (const float*)d_in[0];
    const float* Wres = (const float*)d_in[1];
    const float* wout = (const float*)d_in[2];
    float* out        = (float*)d_out;
    unsigned int* bar = (unsigned int*)d_ws;
    float* gfeats     = (float*)((char*)d_ws + 4096);

    // zero barrier flags (d_ws is re-poisoned before every timed launch)
    (void)hipMemsetAsync(d_ws, 0, 4096, stream);

    void* args[] = { (void*)&x, (void*)&Wres, (void*)&wout, (void*)&out,
                     (void*)&bar, (void*)&gfeats };
    (void)hipLaunchCooperativeKernel((const void*)rc_kernel, dim3(NBLK), dim3(NTHR),
                                     args, 0, stream);
}

// Round 3
// 128882.068 us; speedup vs baseline: 1.0835x; 1.0835x over previous
//
#include <hip/hip_runtime.h>

#define F     4096
#define T     2048
#define ODIM  512
#define NBLK  256
#define NTHR  1024

// d_ws layout:
//   [0, 1024)      : arrive[256]  (u32 per block, monotone step counter)
//   [1280, 1284)   : release      (u32, monotone)
//   [4096, 36864)  : gfeats[2][4096] float ping-pong buffers
// kernel_launch memsets [0,4096) to zero on the stream before the kernel.

template <int CTRL>
__device__ __forceinline__ float dpp_add(float x) {
    int xi = __builtin_bit_cast(int, x);
    int yi = __builtin_amdgcn_update_dpp(0, xi, CTRL, 0xf, 0xf, false);
    return x + __builtin_bit_cast(float, yi);
}

// Full wave64 sum; total lands in lane 63. VALU-only (no LDS-pipe shuffles).
__device__ __forceinline__ float wave_sum(float x) {
    x = dpp_add<0x111>(x); // row_shr:1
    x = dpp_add<0x112>(x); // row_shr:2
    x = dpp_add<0x114>(x); // row_shr:4
    x = dpp_add<0x118>(x); // row_shr:8  -> lane15 of each row has row sum
    x = dpp_add<0x142>(x); // row_bcast:15
    x = dpp_add<0x143>(x); // row_bcast:31 -> lane63 has full sum
    return x;
}

// Pin a float4's components into VGPRs with an opaque producer so the
// compiler can neither rematerialize the load inside the T-loop nor sink it.
#define PIN4(v) asm volatile("" : "+v"((v).x), "+v"((v).y), "+v"((v).z), "+v"((v).w))

__global__ __launch_bounds__(NTHR, 4) void rc_kernel(
    const float* __restrict__ x, const float* __restrict__ Wres,
    const float* __restrict__ wout, float* __restrict__ out,
    unsigned int* __restrict__ bar, float* __restrict__ gfeats)
{
    __shared__ __align__(16) float feats[F];   // 16 KB: current feats vector
    __shared__ float red[16][4];               // per-wave matvec partials
    __shared__ float redo[16];                 // per-wave out partials

    const int tid  = threadIdx.x;
    const int b    = blockIdx.x;
    const int w    = tid >> 6;
    const int lane = tid & 63;
    const int wr   = w & 3;   // row-group (4 rows each)
    const int wk   = w >> 2;  // k-group (1024 k each)

    // ---- persistent W_res fragment: 4 rows x 16 k = 64 fp32 regs ----
    // lane covers k = wk*1024 + i*256 + lane*4 + c   (i=0..3, c=0..3)
    const int row0 = b * 16 + wr * 4;
    float4 wreg[4][4];
    {
        const int kbase = wk * 1024 + lane * 4;
#pragma unroll
        for (int j = 0; j < 4; ++j) {
            const float* wp = Wres + (size_t)(row0 + j) * F + kbase;
#pragma unroll
            for (int i = 0; i < 4; ++i)
                wreg[j][i] = *(const float4*)(wp + i * 256);
        }
    }
#pragma unroll
    for (int j = 0; j < 4; ++j) {
        PIN4(wreg[j][0]); PIN4(wreg[j][1]); PIN4(wreg[j][2]); PIN4(wreg[j][3]);
    }

    // ---- persistent w_out fragment: 8 fp32 regs ----
    // thread handles out row o = b*2 + tid/512, k = kk..kk+3 and 2048+kk..+3
    const int o  = tid >> 9;
    const int kk = (tid & 511) * 4;
    float4 wo_a = *(const float4*)(wout + (size_t)(b * 2 + o) * F + kk);
    float4 wo_b = *(const float4*)(wout + (size_t)(b * 2 + o) * F + 2048 + kk);
    PIN4(wo_a); PIN4(wo_b);

    // ---- init ----
    for (int i = tid; i < F; i += NTHR) feats[i] = 0.f;  // feats_{-1} = 0
    float xval = 0.f;
    if (tid < 16) xval = x[(size_t)(b * 16 + tid) * T + 0];
    __syncthreads();

    unsigned int* arrive  = bar;        // [0..255]
    unsigned int* release = bar + 320;  // own cacheline

    const float4* f4base = (const float4*)feats + wk * 256 + lane;

    for (int t = 0; t < T; ++t) {
        // ---- 1. matvec partials: 64 FMAs/lane on register weights ----
        float acc0 = 0.f, acc1 = 0.f, acc2 = 0.f, acc3 = 0.f;
#pragma unroll
        for (int i = 0; i < 4; ++i) {
            float4 f = f4base[i * 64];  // stride-1 across lanes: conflict-free b128
            acc0 += wreg[0][i].x * f.x + wreg[0][i].y * f.y + wreg[0][i].z * f.z + wreg[0][i].w * f.w;
            acc1 += wreg[1][i].x * f.x + wreg[1][i].y * f.y + wreg[1][i].z * f.z + wreg[1][i].w * f.w;
            acc2 += wreg[2][i].x * f.x + wreg[2][i].y * f.y + wreg[2][i].z * f.z + wreg[2][i].w * f.w;
            acc3 += wreg[3][i].x * f.x + wreg[3][i].y * f.y + wreg[3][i].z * f.z + wreg[3][i].w * f.w;
        }
        // ---- 2. wave-level reduce (VALU DPP), lane63 -> LDS ----
        acc0 = wave_sum(acc0);
        acc1 = wave_sum(acc1);
        acc2 = wave_sum(acc2);
        acc3 = wave_sum(acc3);
        if (lane == 63) {
            red[w][0] = acc0; red[w][1] = acc1; red[w][2] = acc2; red[w][3] = acc3;
        }
        __syncthreads();  // (A)

        // ---- 3. cross-wave reduce, clamp, publish 16 feats components ----
        float* gcur = gfeats + (size_t)(t & 1) * F;
        if (tid < 16) {
            const int r = tid;
            const int rw = r >> 2, rj = r & 3;
            float s = red[rw][rj] + red[rw + 4][rj] + red[rw + 8][rj] + red[rw + 12][rj];
            s += xval;
            s = fminf(1.f, fmaxf(-1.f, s));
            // agent-scope store: write through to the device coherence point
            __hip_atomic_store(&gcur[b * 16 + r], s, __ATOMIC_RELAXED, __HIP_MEMORY_SCOPE_AGENT);
            const int tn = (t + 1 < T) ? (t + 1) : t;
            xval = x[(size_t)(b * 16 + r) * T + tn];  // prefetch next x
        }
        __syncthreads();  // (B) — compiler drains vmcnt(0) before s_barrier:
                          // the 16 data stores (wave 0) are globally visible.

        // ---- 4. grid barrier (wave 0 only; others park at (C)) ----
        if (w == 0) {
            const unsigned int tgt = (unsigned int)(t + 1);
            if (lane == 0)
                __hip_atomic_store(&arrive[b], tgt, __ATOMIC_RELEASE, __HIP_MEMORY_SCOPE_AGENT);
            if (b == 0) {
                bool ok;
                do {
                    unsigned a0 = __hip_atomic_load(&arrive[4 * lane + 0], __ATOMIC_RELAXED, __HIP_MEMORY_SCOPE_AGENT);
                    unsigned a1 = __hip_atomic_load(&arrive[4 * lane + 1], __ATOMIC_RELAXED, __HIP_MEMORY_SCOPE_AGENT);
                    unsigned a2 = __hip_atomic_load(&arrive[4 * lane + 2], __ATOMIC_RELAXED, __HIP_MEMORY_SCOPE_AGENT);
                    unsigned a3 = __hip_atomic_load(&arrive[4 * lane + 3], __ATOMIC_RELAXED, __HIP_MEMORY_SCOPE_AGENT);
                    ok = (a0 >= tgt) && (a1 >= tgt) && (a2 >= tgt) && (a3 >= tgt);
                } while (!__all(ok));
                if (lane == 0)
                    __hip_atomic_store(release, tgt, __ATOMIC_RELEASE, __HIP_MEMORY_SCOPE_AGENT);
            } else if (lane == 0) {
                while (__hip_atomic_load(release, __ATOMIC_RELAXED, __HIP_MEMORY_SCOPE_AGENT) < tgt) { }
            }
        }
        __syncthreads();  // (C)
        __threadfence();  // acquire: invalidate stale cache lines before reading peers' feats

        // ---- 5. stage full feats_t: global -> LDS (1 float4/thread) ----
        float4 v = ((const float4*)gcur)[tid];
        ((float4*)feats)[tid] = v;
        __syncthreads();  // (D)

        // ---- 6. readout: out[o, t] = w_out[o] . feats_t ----
        const float4* fo = (const float4*)feats;
        float4 fa = fo[tid & 511];
        float4 fb = fo[512 + (tid & 511)];
        float p = wo_a.x * fa.x + wo_a.y * fa.y + wo_a.z * fa.z + wo_a.w * fa.w
                + wo_b.x * fb.x + wo_b.y * fb.y + wo_b.z * fb.z + wo_b.w * fb.w;
        p = wave_sum(p);
        if (lane == 63) redo[w] = p;
        __syncthreads();  // (E)
        if (tid < 2) {
            float s = 0.f;
#pragma unroll
            for (int i = 0; i < 8; ++i) s += redo[tid * 8 + i];
            out[(size_t)(b * 2 + tid) * T + t] = s;
        }
    }
}

extern "C" void kernel_launch(void* const* d_in, const int* in_sizes, int n_in,
                              void* d_out, int out_size, void* d_ws, size_t ws_size,
                              hipStream_t stream) {
    const float* x    = (const float*)d_in[0];
    const float* Wres = (const float*)d_in[1];
    const float* wout = (const float*)d_in[2];
    float* out        = (float*)d_out;
    unsigned int* bar = (unsigned int*)d_ws;
    float* gfeats     = (float*)((char*)d_ws + 4096);

    // zero barrier flags (d_ws is re-poisoned before every timed launch)
    (void)hipMemsetAsync(d_ws, 0, 4096, stream);

    void* args[] = { (void*)&x, (void*)&Wres, (void*)&wout, (void*)&out,
                     (void*)&bar, (void*)&gfeats };
    (void)hipLaunchCooperativeKernel((const void*)rc_kernel, dim3(NBLK), dim3(NTHR),
                                     args, 0, stream);
}

// Round 4
// 14436.458 us; speedup vs baseline: 9.6726x; 8.9275x over previous
//
#include <hip/hip_runtime.h>

#define F     4096
#define T     2048
#define NBLK  256
#define NTHR  1024

// d_ws layout:
//   [0, 1024)        : arrive[256]  (u32 per block, monotone step counter)
//   [4096, 36864)    : gfeats[2][4096] float ping-pong buffers
// kernel_launch memsets [0, 36864) to zero on the stream before the kernel.
// feats_{-1} = 0 comes from the zeroed gfeats[1].

template <int CTRL>
__device__ __forceinline__ float dpp_add(float x) {
    int xi = __builtin_bit_cast(int, x);
    int yi = __builtin_amdgcn_update_dpp(0, xi, CTRL, 0xf, 0xf, false);
    return x + __builtin_bit_cast(float, yi);
}

// Full wave64 sum; total lands in lane 63. VALU-only (no LDS-pipe shuffles).
__device__ __forceinline__ float wave_sum(float x) {
    x = dpp_add<0x111>(x); // row_shr:1
    x = dpp_add<0x112>(x); // row_shr:2
    x = dpp_add<0x114>(x); // row_shr:4
    x = dpp_add<0x118>(x); // row_shr:8  -> lane15 of each row has row sum
    x = dpp_add<0x142>(x); // row_bcast:15
    x = dpp_add<0x143>(x); // row_bcast:31 -> lane63 has full sum
    return x;
}

// Keep one-time-loaded values opaque so they stay register-resident.
#define PIN4(v) asm volatile("" : "+v"((v).x), "+v"((v).y), "+v"((v).z), "+v"((v).w))

// Coherent 8-byte load: bypasses stale L1/L2, reads the device coherence
// point. No fences needed anywhere.
__device__ __forceinline__ float2 cload_f2(const float* p) {
    unsigned long long u = __hip_atomic_load((const unsigned long long*)p,
                                             __ATOMIC_RELAXED, __HIP_MEMORY_SCOPE_AGENT);
    union { unsigned long long u; float2 f; } c; c.u = u;
    return c.f;
}

__global__ __launch_bounds__(NTHR, 4) void rc_kernel(
    const float* __restrict__ x, const float* __restrict__ Wres,
    const float* __restrict__ wout, float* __restrict__ out,
    unsigned int* __restrict__ arrive, float* __restrict__ gfeats)
{
    __shared__ float red[16][4];   // per-wave matvec partials
    __shared__ float redo[16];     // per-wave readout partials

    const int tid  = threadIdx.x;
    const int b    = blockIdx.x;
    const int w    = tid >> 6;
    const int lane = tid & 63;
    const int wr   = w & 3;   // row-group (4 rows each)
    const int wk   = w >> 2;  // k-group (1024 k each)

    // ---- persistent W_res fragment: 4 rows x 16 k = 64 fp32 regs/lane ----
    const int row0 = b * 16 + wr * 4;
    float4 wreg[4][4];
    {
        const int kbase = wk * 1024 + lane * 4;
#pragma unroll
        for (int j = 0; j < 4; ++j) {
            const float* wp = Wres + (size_t)(row0 + j) * F + kbase;
#pragma unroll
            for (int i = 0; i < 4; ++i)
                wreg[j][i] = *(const float4*)(wp + i * 256);
        }
    }
#pragma unroll
    for (int j = 0; j < 4; ++j) {
        PIN4(wreg[j][0]); PIN4(wreg[j][1]); PIN4(wreg[j][2]); PIN4(wreg[j][3]);
    }

    // ---- persistent w_out fragment: 8 fp32 regs/thread ----
    const int o  = tid >> 9;
    const int kk = (tid & 511) * 4;
    float4 wo_a = *(const float4*)(wout + (size_t)(b * 2 + o) * F + kk);
    float4 wo_b = *(const float4*)(wout + (size_t)(b * 2 + o) * F + 2048 + kk);
    PIN4(wo_a); PIN4(wo_b);

    // ---- x prefetch for step 0 ----
    float xval = 0.f;
    if (tid < 16) xval = x[(size_t)(b * 16 + tid) * T + 0];

    const int kofs = wk * 1024 + lane * 4;  // this lane's feats base (floats)

    for (int t = 0; t < T; ++t) {
        const float* gprev = gfeats + (size_t)((t & 1) ^ 1) * F;  // feats_{t-1}
        float*       gcur  = gfeats + (size_t)(t & 1) * F;        // feats_t

        // ---- 1. matvec: coherent loads of prev feats + register FMAs ----
        float2 f0a = cload_f2(gprev + kofs + 0*256), f0b = cload_f2(gprev + kofs + 0*256 + 2);
        float2 f1a = cload_f2(gprev + kofs + 1*256), f1b = cload_f2(gprev + kofs + 1*256 + 2);
        float2 f2a = cload_f2(gprev + kofs + 2*256), f2b = cload_f2(gprev + kofs + 2*256 + 2);
        float2 f3a = cload_f2(gprev + kofs + 3*256), f3b = cload_f2(gprev + kofs + 3*256 + 2);

        float acc0 = 0.f, acc1 = 0.f, acc2 = 0.f, acc3 = 0.f;
#define DOT_STEP(i, fa, fb) \
        acc0 += wreg[0][i].x * fa.x + wreg[0][i].y * fa.y + wreg[0][i].z * fb.x + wreg[0][i].w * fb.y; \
        acc1 += wreg[1][i].x * fa.x + wreg[1][i].y * fa.y + wreg[1][i].z * fb.x + wreg[1][i].w * fb.y; \
        acc2 += wreg[2][i].x * fa.x + wreg[2][i].y * fa.y + wreg[2][i].z * fb.x + wreg[2][i].w * fb.y; \
        acc3 += wreg[3][i].x * fa.x + wreg[3][i].y * fa.y + wreg[3][i].z * fb.x + wreg[3][i].w * fb.y;
        DOT_STEP(0, f0a, f0b)
        DOT_STEP(1, f1a, f1b)
        DOT_STEP(2, f2a, f2b)
        DOT_STEP(3, f3a, f3b)
#undef DOT_STEP

        // ---- 2. wave reduce (VALU DPP), lane63 -> LDS ----
        acc0 = wave_sum(acc0);
        acc1 = wave_sum(acc1);
        acc2 = wave_sum(acc2);
        acc3 = wave_sum(acc3);
        if (lane == 63) {
            red[w][0] = acc0; red[w][1] = acc1; red[w][2] = acc2; red[w][3] = acc3;
        }
        __syncthreads();  // (A)

        // ---- 3. combine, clamp, publish 16 feats (coherent stores) ----
        if (tid < 16) {
            const int r = tid, rw = r >> 2, rj = r & 3;
            float s = red[rw][rj] + red[rw + 4][rj] + red[rw + 8][rj] + red[rw + 12][rj];
            s += xval;
            s = fminf(1.f, fmaxf(-1.f, s));
            __hip_atomic_store(&gcur[b * 16 + r], s, __ATOMIC_RELAXED, __HIP_MEMORY_SCOPE_AGENT);
            const int tn = (t + 1 < T) ? (t + 1) : t;
            xval = x[(size_t)(b * 16 + r) * T + tn];  // prefetch next x
        }
        __syncthreads();  // (B) s_waitcnt vmcnt(0): publish stores are
                          // globally visible (write-through) before the flag.

        // ---- 4. grid barrier: all-poll, wave 0 only ----
        if (w == 0) {
            const unsigned int tgt = (unsigned int)(t + 1);
            if (lane == 0)
                __hip_atomic_store(&arrive[b], tgt, __ATOMIC_RELAXED, __HIP_MEMORY_SCOPE_AGENT);
            bool ok;
            do {
                unsigned a0 = __hip_atomic_load(&arrive[4 * lane + 0], __ATOMIC_RELAXED, __HIP_MEMORY_SCOPE_AGENT);
                unsigned a1 = __hip_atomic_load(&arrive[4 * lane + 1], __ATOMIC_RELAXED, __HIP_MEMORY_SCOPE_AGENT);
                unsigned a2 = __hip_atomic_load(&arrive[4 * lane + 2], __ATOMIC_RELAXED, __HIP_MEMORY_SCOPE_AGENT);
                unsigned a3 = __hip_atomic_load(&arrive[4 * lane + 3], __ATOMIC_RELAXED, __HIP_MEMORY_SCOPE_AGENT);
                ok = (a0 >= tgt) && (a1 >= tgt) && (a2 >= tgt) && (a3 >= tgt);
            } while (!__all(ok));
        }
        __syncthreads();  // (C)

        // ---- 5. readout: out[o, t] = w_out[o] . feats_t (coherent loads) ----
        float2 fa0 = cload_f2(gcur + kk),        fa1 = cload_f2(gcur + kk + 2);
        float2 fb0 = cload_f2(gcur + 2048 + kk), fb1 = cload_f2(gcur + 2048 + kk + 2);
        float p = wo_a.x * fa0.x + wo_a.y * fa0.y + wo_a.z * fa1.x + wo_a.w * fa1.y
                + wo_b.x * fb0.x + wo_b.y * fb0.y + wo_b.z * fb1.x + wo_b.w * fb1.y;
        p = wave_sum(p);
        if (lane == 63) redo[w] = p;
        __syncthreads();  // (E)
        if (tid < 2) {
            float s = 0.f;
#pragma unroll
            for (int i = 0; i < 8; ++i) s += redo[tid * 8 + i];
            out[(size_t)(b * 2 + tid) * T + t] = s;
        }
    }
}

extern "C" void kernel_launch(void* const* d_in, const int* in_sizes, int n_in,
                              void* d_out, int out_size, void* d_ws, size_t ws_size,
                              hipStream_t stream) {
    const float* x    = (const float*)d_in[0];
    const float* Wres = (const float*)d_in[1];
    const float* wout = (const float*)d_in[2];
    float* out        = (float*)d_out;
    unsigned int* bar = (unsigned int*)d_ws;
    float* gfeats     = (float*)((char*)d_ws + 4096);

    // zero barrier flags + both gfeats buffers (feats_{-1}=0 needs gfeats[1]=0)
    (void)hipMemsetAsync(d_ws, 0, 4096 + 2 * F * sizeof(float), stream);

    void* args[] = { (void*)&x, (void*)&Wres, (void*)&wout, (void*)&out,
                     (void*)&bar, (void*)&gfeats };
    (void)hipLaunchCooperativeKernel((const void*)rc_kernel, dim3(NBLK), dim3(NTHR),
                                     args, 0, stream);
}

// Round 5
// 12646.867 us; speedup vs baseline: 11.0413x; 1.1415x over previous
//
#include <hip/hip_runtime.h>

#define F     4096
#define T     2048
#define NBLK  256
#define NTHR  1024

// d_ws layout:
//   [0, 4)         : cnt  (u32 monotone arrival counter, reaches 256*2048)
//   [4096, 36864)  : gfeats[2][4096] float ping-pong buffers
// kernel_launch memsets [0, 36864) to zero. feats_{-1}=0 = zeroed gfeats[1].

template <int CTRL>
__device__ __forceinline__ float dpp_add(float x) {
    int xi = __builtin_bit_cast(int, x);
    int yi = __builtin_amdgcn_update_dpp(0, xi, CTRL, 0xf, 0xf, false);
    return x + __builtin_bit_cast(float, yi);
}

// Full wave64 sum; total lands in lane 63. VALU-only.
__device__ __forceinline__ float wave_sum(float x) {
    x = dpp_add<0x111>(x); // row_shr:1
    x = dpp_add<0x112>(x); // row_shr:2
    x = dpp_add<0x114>(x); // row_shr:4
    x = dpp_add<0x118>(x); // row_shr:8
    x = dpp_add<0x142>(x); // row_bcast:15
    x = dpp_add<0x143>(x); // row_bcast:31
    return x;
}

#define PIN4(v) asm volatile("" : "+v"((v).x), "+v"((v).y), "+v"((v).z), "+v"((v).w))

// Coherent 8B load: bypasses stale L1/L2, reads device coherence point (L3).
__device__ __forceinline__ float2 cload_f2(const float* p) {
    unsigned long long u = __hip_atomic_load((const unsigned long long*)p,
                                             __ATOMIC_RELAXED, __HIP_MEMORY_SCOPE_AGENT);
    union { unsigned long long u; float2 f; } c; c.u = u;
    return c.f;
}

__global__ __launch_bounds__(NTHR, 4) void rc_kernel(
    const float* __restrict__ x, const float* __restrict__ Wres,
    const float* __restrict__ wout, float* __restrict__ out,
    unsigned int* __restrict__ cnt, float* __restrict__ gfeats)
{
    __shared__ float red[16][4];   // per-wave matvec partials
    __shared__ float redo[16];     // per-wave readout partials

    const int tid  = threadIdx.x;
    const int b    = blockIdx.x;
    const int w    = tid >> 6;
    const int lane = tid & 63;
    const int wr   = w & 3;   // row-group (4 rows each)
    const int wk   = w >> 2;  // k-group (1024 k each)

    // ---- persistent W_res fragment: 4 rows x 16 k = 64 fp32 regs/lane ----
    const int row0 = b * 16 + wr * 4;
    const int kofs = wk * 1024 + lane * 4;  // this lane's feats base (floats)
    float4 wreg[4][4];
#pragma unroll
    for (int j = 0; j < 4; ++j) {
        const float* wp = Wres + (size_t)(row0 + j) * F + kofs;
#pragma unroll
        for (int i = 0; i < 4; ++i)
            wreg[j][i] = *(const float4*)(wp + i * 256);
    }
#pragma unroll
    for (int j = 0; j < 4; ++j) {
        PIN4(wreg[j][0]); PIN4(wreg[j][1]); PIN4(wreg[j][2]); PIN4(wreg[j][3]);
    }

    // ---- persistent w_out fragment (fused readout): 8 fp32 regs/lane ----
    // wave (wr,wk) covers out-row b*2+(wr&1), chunks i0,i0+1 of segment wk.
    const int rrow = b * 2 + (wr & 1);
    const int i0   = (wr >> 1) * 2;
    const float* wop = wout + (size_t)rrow * F + kofs + i0 * 256;
    float4 wo0 = *(const float4*)(wop);
    float4 wo1 = *(const float4*)(wop + 256);
    PIN4(wo0); PIN4(wo1);

    // ---- x prefetch for step 0 ----
    float xval = 0.f;
    if (tid < 16) xval = x[(size_t)(b * 16 + tid) * T + 0];

    for (int t = 0; t < T; ++t) {
        const float* gprev = gfeats + (size_t)((t & 1) ^ 1) * F;  // feats_{t-1}
        float*       gcur  = gfeats + (size_t)(t & 1) * F;        // feats_t

        // ---- 1. barrier wait: all blocks have published feats_{t-1} ----
        if (t > 0 && w == 0 && lane == 0) {
            const unsigned int tgt = (unsigned int)t * NBLK;
            while (__hip_atomic_load(cnt, __ATOMIC_RELAXED, __HIP_MEMORY_SCOPE_AGENT) < tgt) { }
        }
        __syncthreads();  // (C)

        // ---- 2. single coherent load phase: 16 floats of feats_{t-1} ----
        float2 f0a = cload_f2(gprev + kofs + 0*256), f0b = cload_f2(gprev + kofs + 0*256 + 2);
        float2 f1a = cload_f2(gprev + kofs + 1*256), f1b = cload_f2(gprev + kofs + 1*256 + 2);
        float2 f2a = cload_f2(gprev + kofs + 2*256), f2b = cload_f2(gprev + kofs + 2*256 + 2);
        float2 f3a = cload_f2(gprev + kofs + 3*256), f3b = cload_f2(gprev + kofs + 3*256 + 2);

        // ---- 3. matvec partials: 64 FMAs on register weights ----
        float acc0 = 0.f, acc1 = 0.f, acc2 = 0.f, acc3 = 0.f;
#define DOT_STEP(i, fa, fb) \
        acc0 += wreg[0][i].x * fa.x + wreg[0][i].y * fa.y + wreg[0][i].z * fb.x + wreg[0][i].w * fb.y; \
        acc1 += wreg[1][i].x * fa.x + wreg[1][i].y * fa.y + wreg[1][i].z * fb.x + wreg[1][i].w * fb.y; \
        acc2 += wreg[2][i].x * fa.x + wreg[2][i].y * fa.y + wreg[2][i].z * fb.x + wreg[2][i].w * fb.y; \
        acc3 += wreg[3][i].x * fa.x + wreg[3][i].y * fa.y + wreg[3][i].z * fb.x + wreg[3][i].w * fb.y;
        DOT_STEP(0, f0a, f0b)
        DOT_STEP(1, f1a, f1b)
        DOT_STEP(2, f2a, f2b)
        DOT_STEP(3, f3a, f3b)
#undef DOT_STEP

        // ---- 4. fused readout partial for out[:, t-1] (same registers) ----
        float2 ra0, rb0, ra1, rb1;
        if (i0 == 0) { ra0 = f0a; rb0 = f0b; ra1 = f1a; rb1 = f1b; }
        else         { ra0 = f2a; rb0 = f2b; ra1 = f3a; rb1 = f3b; }
        float p = wo0.x * ra0.x + wo0.y * ra0.y + wo0.z * rb0.x + wo0.w * rb0.y
                + wo1.x * ra1.x + wo1.y * ra1.y + wo1.z * rb1.x + wo1.w * rb1.y;

        // ---- 5. wave reduce (VALU DPP), lane63 -> LDS ----
        acc0 = wave_sum(acc0);
        acc1 = wave_sum(acc1);
        acc2 = wave_sum(acc2);
        acc3 = wave_sum(acc3);
        p    = wave_sum(p);
        if (lane == 63) {
            red[w][0] = acc0; red[w][1] = acc1; red[w][2] = acc2; red[w][3] = acc3;
            redo[w] = p;
        }
        __syncthreads();  // (A)

        // ---- 6. combine+clamp+publish feats_t; write out[:, t-1] ----
        if (tid < 16) {
            const int r = tid, rw = r >> 2, rj = r & 3;
            float s = red[rw][rj] + red[rw + 4][rj] + red[rw + 8][rj] + red[rw + 12][rj];
            s += xval;
            s = fminf(1.f, fmaxf(-1.f, s));
            __hip_atomic_store(&gcur[b * 16 + r], s, __ATOMIC_RELAXED, __HIP_MEMORY_SCOPE_AGENT);
            const int tn = (t + 1 < T) ? (t + 1) : t;
            xval = x[(size_t)(b * 16 + r) * T + tn];  // prefetch next x
        } else if (tid >= 64 && tid < 66 && t > 0) {
            const int r = tid - 64;   // out rows b*2, b*2+1; even/odd waves
            float s = redo[r] + redo[r + 2] + redo[r + 4] + redo[r + 6]
                    + redo[r + 8] + redo[r + 10] + redo[r + 12] + redo[r + 14];
            out[(size_t)(b * 2 + r) * T + (t - 1)] = s;
        }
        __syncthreads();  // (B) vmcnt(0) drain: publish stores globally visible

        // ---- 7. fire-and-forget arrival ----
        if (tid == 0)
            __hip_atomic_fetch_add(cnt, 1u, __ATOMIC_RELAXED, __HIP_MEMORY_SCOPE_AGENT);
    }

    // ---- tail: readout for t = T-1 ----
    if (w == 0 && lane == 0) {
        const unsigned int tgt = (unsigned int)T * NBLK;
        while (__hip_atomic_load(cnt, __ATOMIC_RELAXED, __HIP_MEMORY_SCOPE_AGENT) < tgt) { }
    }
    __syncthreads();
    {
        const float* glast = gfeats + (size_t)((T - 1) & 1) * F;  // feats_{T-1}
        float2 ta0 = cload_f2(glast + kofs + i0 * 256);
        float2 tb0 = cload_f2(glast + kofs + i0 * 256 + 2);
        float2 ta1 = cload_f2(glast + kofs + (i0 + 1) * 256);
        float2 tb1 = cload_f2(glast + kofs + (i0 + 1) * 256 + 2);
        float p = wo0.x * ta0.x + wo0.y * ta0.y + wo0.z * tb0.x + wo0.w * tb0.y
                + wo1.x * ta1.x + wo1.y * ta1.y + wo1.z * tb1.x + wo1.w * tb1.y;
        p = wave_sum(p);
        if (lane == 63) redo[w] = p;
        __syncthreads();
        if (tid < 2) {
            float s = redo[tid] + redo[tid + 2] + redo[tid + 4] + redo[tid + 6]
                    + redo[tid + 8] + redo[tid + 10] + redo[tid + 12] + redo[tid + 14];
            out[(size_t)(b * 2 + tid) * T + (T - 1)] = s;
        }
    }
}

extern "C" void kernel_launch(void* const* d_in, const int* in_sizes, int n_in,
                              void* d_out, int out_size, void* d_ws, size_t ws_size,
                              hipStream_t stream) {
    const float* x    = (const float*)d_in[0];
    const float* Wres = (const float*)d_in[1];
    const float* wout = (const float*)d_in[2];
    float* out        = (float*)d_out;
    unsigned int* cnt = (unsigned int*)d_ws;
    float* gfeats     = (float*)((char*)d_ws + 4096);

    // zero counter + both gfeats buffers (feats_{-1}=0 needs gfeats[1]=0)
    (void)hipMemsetAsync(d_ws, 0, 4096 + 2 * F * sizeof(float), stream);

    void* args[] = { (void*)&x, (void*)&Wres, (void*)&wout, (void*)&out,
                     (void*)&cnt, (void*)&gfeats };
    (void)hipLaunchCooperativeKernel((const void*)rc_kernel, dim3(NBLK), dim3(NTHR),
                                     args, 0, stream);
}

// Round 6
// 9304.318 us; speedup vs baseline: 15.0079x; 1.3592x over previous
//
#include <hip/hip_runtime.h>

#define F     4096
#define T     2048
#define NBLK  256
#define NTHR  1024
#define K     4      // ring slots (power of 2)

// d_ws layout:
//   [0, 1024)              : done[16] counters, 64 B apart (memset 0 each launch)
//   [4096, 4096 + K*F*8)   : ring[K][4096] of {f32 val, u32 tag} pairs (NOT memset:
//                            tags are self-describing; 0xAA poison never matches)

template <int CTRL>
__device__ __forceinline__ float dpp_add(float x) {
    int xi = __builtin_bit_cast(int, x);
    int yi = __builtin_amdgcn_update_dpp(0, xi, CTRL, 0xf, 0xf, false);
    return x + __builtin_bit_cast(float, yi);
}

// Full wave64 sum; total lands in lane 63. VALU-only.
__device__ __forceinline__ float wave_sum(float x) {
    x = dpp_add<0x111>(x); // row_shr:1
    x = dpp_add<0x112>(x); // row_shr:2
    x = dpp_add<0x114>(x); // row_shr:4
    x = dpp_add<0x118>(x); // row_shr:8
    x = dpp_add<0x142>(x); // row_bcast:15
    x = dpp_add<0x143>(x); // row_bcast:31
    return x;
}

#define PIN4(v) asm volatile("" : "+v"((v).x), "+v"((v).y), "+v"((v).z), "+v"((v).w))

typedef unsigned long long u64;
typedef unsigned int u32;

__device__ __forceinline__ u64 cload_u64(const u64* p) {
    return __hip_atomic_load(p, __ATOMIC_RELAXED, __HIP_MEMORY_SCOPE_AGENT);
}
__device__ __forceinline__ void cstore_u64(u64* p, u64 v) {
    __hip_atomic_store(p, v, __ATOMIC_RELAXED, __HIP_MEMORY_SCOPE_AGENT);
}
__device__ __forceinline__ u32 cload_u32(const u32* p) {
    return __hip_atomic_load(p, __ATOMIC_RELAXED, __HIP_MEMORY_SCOPE_AGENT);
}

__global__ __launch_bounds__(NTHR, 4) void rc_kernel(
    const float* __restrict__ x, const float* __restrict__ Wres,
    const float* __restrict__ wout, float* __restrict__ out,
    u32* __restrict__ done, u64* __restrict__ ring)
{
    __shared__ __align__(16) float fl[F];     // staged feats vector (16 KB)
    __shared__ float red[2][16][4];           // double-buffered matvec partials
    __shared__ float redo[2][16];             // double-buffered readout partials

    const int tid  = threadIdx.x;
    const int b    = blockIdx.x;
    const int w    = tid >> 6;
    const int lane = tid & 63;
    const int wr   = w & 3;   // row-group (4 rows each)
    const int wk   = w >> 2;  // k-group (1024 k each)

    // ---- persistent W_res fragment: 4 rows x 16 k = 64 fp32 regs/lane ----
    const int row0 = b * 16 + wr * 4;
    const int kofs = wk * 1024 + lane * 4;
    float4 wreg[4][4];
#pragma unroll
    for (int j = 0; j < 4; ++j) {
        const float* wp = Wres + (size_t)(row0 + j) * F + kofs;
#pragma unroll
        for (int i = 0; i < 4; ++i)
            wreg[j][i] = *(const float4*)(wp + i * 256);
    }
#pragma unroll
    for (int j = 0; j < 4; ++j) {
        PIN4(wreg[j][0]); PIN4(wreg[j][1]); PIN4(wreg[j][2]); PIN4(wreg[j][3]);
    }

    // ---- persistent w_out fragment (fused readout): 8 fp32 regs/lane ----
    const int rrow = b * 2 + (wr & 1);
    const int i0   = (wr >> 1) * 2;
    const float* wop = wout + (size_t)rrow * F + kofs + i0 * 256;
    float4 wo0 = *(const float4*)(wop);
    float4 wo1 = *(const float4*)(wop + 256);
    PIN4(wo0); PIN4(wo1);

    // ---- x prefetch for step 0 ----
    float xval = 0.f;
    if (tid < 16) xval = x[(size_t)(b * 16 + tid) * T + 0];

    const int ep = w * 256 + lane * 4;  // this lane's poll chunk base (elements)

    for (int t = 0; t <= T; ++t) {
        // ---- 1. poll feats_{t-1} pairs (tag == t) and stage to LDS ----
        if (t > 0) {
            const u64* rs = ring + (size_t)((t - 1) & (K - 1)) * F + ep;
            const u32 tag = (u32)t;
            u64 p0 = cload_u64(rs + 0), p1 = cload_u64(rs + 1);
            u64 p2 = cload_u64(rs + 2), p3 = cload_u64(rs + 3);
            bool ok = ((u32)(p0 >> 32) == tag) & ((u32)(p1 >> 32) == tag)
                    & ((u32)(p2 >> 32) == tag) & ((u32)(p3 >> 32) == tag);
            while (!__all(ok)) {
                if (!ok) {
                    __builtin_amdgcn_s_sleep(1);
                    p0 = cload_u64(rs + 0); p1 = cload_u64(rs + 1);
                    p2 = cload_u64(rs + 2); p3 = cload_u64(rs + 3);
                    ok = ((u32)(p0 >> 32) == tag) & ((u32)(p1 >> 32) == tag)
                       & ((u32)(p2 >> 32) == tag) & ((u32)(p3 >> 32) == tag);
                }
            }
            float4 v;
            v.x = __builtin_bit_cast(float, (u32)p0);
            v.y = __builtin_bit_cast(float, (u32)p1);
            v.z = __builtin_bit_cast(float, (u32)p2);
            v.w = __builtin_bit_cast(float, (u32)p3);
            *(float4*)&fl[ep] = v;
        } else {
            *(float4*)&fl[ep] = make_float4(0.f, 0.f, 0.f, 0.f);  // feats_{-1}=0
        }

        // ---- 2. capacity preload (wave 0; latency hides under step) ----
        u32 dv = 0;
        if (w == 0 && t < T) dv = cload_u32(done + (lane & 15) * 16);

        __syncthreads();  // (L) feats staged

        // ---- 3. signal "block done reading step-t data" (fire & forget) ----
        if (tid == 64)
            __hip_atomic_fetch_add(&done[(b & 15) * 16], 1u,
                                   __ATOMIC_RELAXED, __HIP_MEMORY_SCOPE_AGENT);

        // ---- 4. matvec from LDS + fused readout partial ----
        float4 f0 = *(const float4*)&fl[kofs + 0 * 256];
        float4 f1 = *(const float4*)&fl[kofs + 1 * 256];
        float4 f2 = *(const float4*)&fl[kofs + 2 * 256];
        float4 f3 = *(const float4*)&fl[kofs + 3 * 256];

        float acc0 = 0.f, acc1 = 0.f, acc2 = 0.f, acc3 = 0.f;
#define DOT_STEP(i, fv) \
        acc0 += wreg[0][i].x * fv.x + wreg[0][i].y * fv.y + wreg[0][i].z * fv.z + wreg[0][i].w * fv.w; \
        acc1 += wreg[1][i].x * fv.x + wreg[1][i].y * fv.y + wreg[1][i].z * fv.z + wreg[1][i].w * fv.w; \
        acc2 += wreg[2][i].x * fv.x + wreg[2][i].y * fv.y + wreg[2][i].z * fv.z + wreg[2][i].w * fv.w; \
        acc3 += wreg[3][i].x * fv.x + wreg[3][i].y * fv.y + wreg[3][i].z * fv.z + wreg[3][i].w * fv.w;
        DOT_STEP(0, f0)
        DOT_STEP(1, f1)
        DOT_STEP(2, f2)
        DOT_STEP(3, f3)
#undef DOT_STEP

        float4 ra, rb;
        if (i0 == 0) { ra = f0; rb = f1; } else { ra = f2; rb = f3; }
        float p = wo0.x * ra.x + wo0.y * ra.y + wo0.z * ra.z + wo0.w * ra.w
                + wo1.x * rb.x + wo1.y * rb.y + wo1.z * rb.z + wo1.w * rb.w;

        // ---- 5. wave reduce, lane63 -> LDS (double-buffered by t&1) ----
        acc0 = wave_sum(acc0);
        acc1 = wave_sum(acc1);
        acc2 = wave_sum(acc2);
        acc3 = wave_sum(acc3);
        p    = wave_sum(p);
        const int pb = t & 1;
        if (lane == 63) {
            red[pb][w][0] = acc0; red[pb][w][1] = acc1;
            red[pb][w][2] = acc2; red[pb][w][3] = acc3;
            redo[pb][w] = p;
        }
        __syncthreads();  // (A)

        // ---- 6. wave 0: capacity gate, combine, clamp, publish tagged ----
        if (w == 0 && t < T) {
            const int need = 16 * (t - K + 2);
            bool cok = (need <= 0) || ((int)dv >= need);
            while (!__all(cok)) {
                if (!cok) {
                    __builtin_amdgcn_s_sleep(1);
                    dv = cload_u32(done + (lane & 15) * 16);
                    cok = ((int)dv >= need);
                }
            }
            if (lane < 16) {
                const int r = lane, rw = r >> 2, rj = r & 3;
                float s = red[pb][rw][rj] + red[pb][rw + 4][rj]
                        + red[pb][rw + 8][rj] + red[pb][rw + 12][rj];
                s += xval;
                s = fminf(1.f, fmaxf(-1.f, s));
                u64 pk = ((u64)(u32)(t + 1) << 32) | (u64)__builtin_bit_cast(u32, s);
                cstore_u64(ring + (size_t)(t & (K - 1)) * F + b * 16 + r, pk);
                const int tn = (t + 1 < T) ? (t + 1) : (T - 1);
                xval = x[(size_t)(b * 16 + r) * T + tn];  // off critical path
            }
        }

        // ---- 7. out[:, t-1] store (wave 1; off the publish path) ----
        if (t > 0 && tid >= 64 && tid < 66) {
            const int r = tid - 64;
            float s = redo[pb][r]      + redo[pb][r + 2]  + redo[pb][r + 4]
                    + redo[pb][r + 6]  + redo[pb][r + 8]  + redo[pb][r + 10]
                    + redo[pb][r + 12] + redo[pb][r + 14];
            out[(size_t)(b * 2 + r) * T + (t - 1)] = s;
        }
        // no trailing barrier: red/redo are double-buffered; fl rewrite at t+1
        // is separated from this step's reads by sync (A); cross-block reuse of
        // ring slots is gated by the done counters.
    }
}

extern "C" void kernel_launch(void* const* d_in, const int* in_sizes, int n_in,
                              void* d_out, int out_size, void* d_ws, size_t ws_size,
                              hipStream_t stream) {
    const float* x    = (const float*)d_in[0];
    const float* Wres = (const float*)d_in[1];
    const float* wout = (const float*)d_in[2];
    float* out        = (float*)d_out;
    u32* done         = (u32*)d_ws;
    u64* ring         = (u64*)((char*)d_ws + 4096);

    // zero only the done counters; ring tags are self-describing
    (void)hipMemsetAsync(d_ws, 0, 1024, stream);

    void* args[] = { (void*)&x, (void*)&Wres, (void*)&wout, (void*)&out,
                     (void*)&done, (void*)&ring };
    (void)hipLaunchCooperativeKernel((const void*)rc_kernel, dim3(NBLK), dim3(NTHR),
                                     args, 0, stream);
}

// Round 7
// 9279.298 us; speedup vs baseline: 15.0483x; 1.0027x over previous
//
#include <hip/hip_runtime.h>

#define F     4096
#define T     2048
#define NBLK  256
#define NTHR  1024
#define K     4      // ring slots (power of 2)

// d_ws layout:
//   [0, 1024)              : done[16] counters, 64 B apart (memset 0 each launch)
//   [4096, 4096 + K*F*8)   : ring[K][4096] of {f32 val, u32 tag} pairs (NOT memset:
//                            tags are self-describing; 0xAA poison never matches)

template <int CTRL>
__device__ __forceinline__ float dpp_add(float x) {
    int xi = __builtin_bit_cast(int, x);
    int yi = __builtin_amdgcn_update_dpp(0, xi, CTRL, 0xf, 0xf, false);
    return x + __builtin_bit_cast(float, yi);
}

// Full wave64 sum; total lands in lane 63. VALU-only.
__device__ __forceinline__ float wave_sum(float x) {
    x = dpp_add<0x111>(x); // row_shr:1
    x = dpp_add<0x112>(x); // row_shr:2
    x = dpp_add<0x114>(x); // row_shr:4
    x = dpp_add<0x118>(x); // row_shr:8
    x = dpp_add<0x142>(x); // row_bcast:15
    x = dpp_add<0x143>(x); // row_bcast:31
    return x;
}

#define PIN4(v) asm volatile("" : "+v"((v).x), "+v"((v).y), "+v"((v).z), "+v"((v).w))

typedef unsigned long long u64;
typedef unsigned int u32;

__device__ __forceinline__ u64 cload_u64(const u64* p) {
    return __hip_atomic_load(p, __ATOMIC_RELAXED, __HIP_MEMORY_SCOPE_AGENT);
}
__device__ __forceinline__ void cstore_u64(u64* p, u64 v) {
    __hip_atomic_store(p, v, __ATOMIC_RELAXED, __HIP_MEMORY_SCOPE_AGENT);
}
__device__ __forceinline__ u32 cload_u32(const u32* p) {
    return __hip_atomic_load(p, __ATOMIC_RELAXED, __HIP_MEMORY_SCOPE_AGENT);
}

__global__ __launch_bounds__(NTHR, 4) void rc_kernel(
    const float* __restrict__ x, const float* __restrict__ Wres,
    const float* __restrict__ wout, float* __restrict__ out,
    u32* __restrict__ done, u64* __restrict__ ring)
{
    __shared__ __align__(16) float fl[F];     // staged feats vector (16 KB)
    __shared__ float red[2][16][4];           // double-buffered matvec partials
    __shared__ float redo[2][16];             // double-buffered readout partials

    const int tid  = threadIdx.x;
    const int b    = blockIdx.x;
    const int w    = tid >> 6;
    const int lane = tid & 63;
    const int wr   = w & 3;   // row-group (4 rows each)
    const int wk   = w >> 2;  // k-group (1024 k each)

    // ---- persistent W_res fragment: 4 rows x 16 k = 64 fp32 regs/lane ----
    const int row0 = b * 16 + wr * 4;
    const int kofs = wk * 1024 + lane * 4;
    float4 wreg[4][4];
#pragma unroll
    for (int j = 0; j < 4; ++j) {
        const float* wp = Wres + (size_t)(row0 + j) * F + kofs;
#pragma unroll
        for (int i = 0; i < 4; ++i)
            wreg[j][i] = *(const float4*)(wp + i * 256);
    }
#pragma unroll
    for (int j = 0; j < 4; ++j) {
        PIN4(wreg[j][0]); PIN4(wreg[j][1]); PIN4(wreg[j][2]); PIN4(wreg[j][3]);
    }

    // ---- persistent w_out fragment (fused readout): 8 fp32 regs/lane ----
    const int rrow = b * 2 + (wr & 1);
    const int i0   = (wr >> 1) * 2;
    const float* wop = wout + (size_t)rrow * F + kofs + i0 * 256;
    float4 wo0 = *(const float4*)(wop);
    float4 wo1 = *(const float4*)(wop + 256);
    PIN4(wo0); PIN4(wo1);

    // ---- x prefetch for step 0 ----
    float xval = 0.f;
    if (tid < 16) xval = x[(size_t)(b * 16 + tid) * T + 0];

    const int ep = w * 256 + lane * 4;  // this lane's poll chunk base (elements)

    for (int t = 0; t <= T; ++t) {
        // ---- 1. poll feats_{t-1} pairs (tag == t) and stage to LDS ----
        // Predicated retry: only still-stale pairs re-load (exec-masked),
        // so retry rounds cost ~zero fabric bandwidth in steady state.
        if (t > 0) {
            const u64* rs = ring + (size_t)((t - 1) & (K - 1)) * F + ep;
            const u32 tag = (u32)t;
            u64 p0 = cload_u64(rs + 0), p1 = cload_u64(rs + 1);
            u64 p2 = cload_u64(rs + 2), p3 = cload_u64(rs + 3);
            bool ok0 = ((u32)(p0 >> 32) == tag), ok1 = ((u32)(p1 >> 32) == tag);
            bool ok2 = ((u32)(p2 >> 32) == tag), ok3 = ((u32)(p3 >> 32) == tag);
            while (!__all(ok0 & ok1 & ok2 & ok3)) {
                __builtin_amdgcn_s_sleep(1);
                if (!ok0) { p0 = cload_u64(rs + 0); ok0 = ((u32)(p0 >> 32) == tag); }
                if (!ok1) { p1 = cload_u64(rs + 1); ok1 = ((u32)(p1 >> 32) == tag); }
                if (!ok2) { p2 = cload_u64(rs + 2); ok2 = ((u32)(p2 >> 32) == tag); }
                if (!ok3) { p3 = cload_u64(rs + 3); ok3 = ((u32)(p3 >> 32) == tag); }
            }
            float4 v;
            v.x = __builtin_bit_cast(float, (u32)p0);
            v.y = __builtin_bit_cast(float, (u32)p1);
            v.z = __builtin_bit_cast(float, (u32)p2);
            v.w = __builtin_bit_cast(float, (u32)p3);
            *(float4*)&fl[ep] = v;
        } else {
            *(float4*)&fl[ep] = make_float4(0.f, 0.f, 0.f, 0.f);  // feats_{-1}=0
        }

        // ---- 2. capacity preload (wave 0; latency hides under step) ----
        u32 dv = 0;
        if (w == 0 && t < T) dv = cload_u32(done + (lane & 15) * 16);

        __syncthreads();  // (L) feats staged

        // ---- 3. signal "block done reading step-t data" (fire & forget) ----
        if (tid == 64)
            __hip_atomic_fetch_add(&done[(b & 15) * 16], 1u,
                                   __ATOMIC_RELAXED, __HIP_MEMORY_SCOPE_AGENT);

        // ---- 4. matvec from LDS + fused readout partial ----
        float4 f0 = *(const float4*)&fl[kofs + 0 * 256];
        float4 f1 = *(const float4*)&fl[kofs + 1 * 256];
        float4 f2 = *(const float4*)&fl[kofs + 2 * 256];
        float4 f3 = *(const float4*)&fl[kofs + 3 * 256];

        float acc0 = 0.f, acc1 = 0.f, acc2 = 0.f, acc3 = 0.f;
#define DOT_STEP(i, fv) \
        acc0 += wreg[0][i].x * fv.x + wreg[0][i].y * fv.y + wreg[0][i].z * fv.z + wreg[0][i].w * fv.w; \
        acc1 += wreg[1][i].x * fv.x + wreg[1][i].y * fv.y + wreg[1][i].z * fv.z + wreg[1][i].w * fv.w; \
        acc2 += wreg[2][i].x * fv.x + wreg[2][i].y * fv.y + wreg[2][i].z * fv.z + wreg[2][i].w * fv.w; \
        acc3 += wreg[3][i].x * fv.x + wreg[3][i].y * fv.y + wreg[3][i].z * fv.z + wreg[3][i].w * fv.w;
        DOT_STEP(0, f0)
        DOT_STEP(1, f1)
        DOT_STEP(2, f2)
        DOT_STEP(3, f3)
#undef DOT_STEP

        float4 ra, rb;
        if (i0 == 0) { ra = f0; rb = f1; } else { ra = f2; rb = f3; }
        float p = wo0.x * ra.x + wo0.y * ra.y + wo0.z * ra.z + wo0.w * ra.w
                + wo1.x * rb.x + wo1.y * rb.y + wo1.z * rb.z + wo1.w * rb.w;

        // ---- 5. wave reduce, lane63 -> LDS (double-buffered by t&1) ----
        acc0 = wave_sum(acc0);
        acc1 = wave_sum(acc1);
        acc2 = wave_sum(acc2);
        acc3 = wave_sum(acc3);
        p    = wave_sum(p);
        const int pb = t & 1;
        if (lane == 63) {
            red[pb][w][0] = acc0; red[pb][w][1] = acc1;
            red[pb][w][2] = acc2; red[pb][w][3] = acc3;
            redo[pb][w] = p;
        }
        __syncthreads();  // (A)

        // ---- 6. wave 0: capacity gate, combine, clamp, publish tagged ----
        if (w == 0 && t < T) {
            const int need = 16 * (t - K + 2);
            bool cok = (need <= 0) || ((int)dv >= need);
            while (!__all(cok)) {
                if (!cok) {
                    __builtin_amdgcn_s_sleep(1);
                    dv = cload_u32(done + (lane & 15) * 16);
                    cok = ((int)dv >= need);
                }
            }
            if (lane < 16) {
                const int r = lane, rw = r >> 2, rj = r & 3;
                float s = red[pb][rw][rj] + red[pb][rw + 4][rj]
                        + red[pb][rw + 8][rj] + red[pb][rw + 12][rj];
                s += xval;
                s = fminf(1.f, fmaxf(-1.f, s));
                u64 pk = ((u64)(u32)(t + 1) << 32) | (u64)__builtin_bit_cast(u32, s);
                cstore_u64(ring + (size_t)(t & (K - 1)) * F + b * 16 + r, pk);
                const int tn = (t + 1 < T) ? (t + 1) : (T - 1);
                xval = x[(size_t)(b * 16 + r) * T + tn];  // off critical path
            }
        }

        // ---- 7. out[:, t-1] store (wave 1; off the publish path) ----
        if (t > 0 && tid >= 64 && tid < 66) {
            const int r = tid - 64;
            float s = redo[pb][r]      + redo[pb][r + 2]  + redo[pb][r + 4]
                    + redo[pb][r + 6]  + redo[pb][r + 8]  + redo[pb][r + 10]
                    + redo[pb][r + 12] + redo[pb][r + 14];
            out[(size_t)(b * 2 + r) * T + (t - 1)] = s;
        }
        // no trailing barrier: red/redo are double-buffered; fl rewrite at t+1
        // is separated from this step's reads by sync (A); cross-block reuse of
        // ring slots is gated by the done counters.
    }
}

extern "C" void kernel_launch(void* const* d_in, const int* in_sizes, int n_in,
                              void* d_out, int out_size, void* d_ws, size_t ws_size,
                              hipStream_t stream) {
    const float* x    = (const float*)d_in[0];
    const float* Wres = (const float*)d_in[1];
    const float* wout = (const float*)d_in[2];
    float* out        = (float*)d_out;
    u32* done         = (u32*)d_ws;
    u64* ring         = (u64*)((char*)d_ws + 4096);

    // zero only the done counters; ring tags are self-describing
    (void)hipMemsetAsync(d_ws, 0, 1024, stream);

    void* args[] = { (void*)&x, (void*)&Wres, (void*)&wout, (void*)&out,
                     (void*)&done, (void*)&ring };
    (void)hipLaunchCooperativeKernel((const void*)rc_kernel, dim3(NBLK), dim3(NTHR),
                                     args, 0, stream);
}